// Round 14
// baseline (75.081 us; speedup 1.0000x reference)
//
#include <hip/hip_runtime.h>
#include <hip/hip_bf16.h>
#include <stdint.h>

// MQA attention, bf16 MFMA pipeline.
// B=2, S=2048, D_MODEL=1024, H=16, DK=64. Causal mask applied analytically.
//
// R27: gemm co-residency probe. Counters (MfmaUtil 15/13, VALUBusy ~8,
// HBM ~20%, Occupancy 13.7%) show the gemms are LATENCY-bound, not
// pipe-bound (the old "LDS floor" model over-predicted by 2x). N-tile
// 128 -> 64: Bs halves -> LDS 32KB -> 5 blocks/CU (20 waves/CU, was 12).
// Same staging/swizzle/fragment algebra (A path byte-identical; B path
// same linear-dest formula with q<2; b-frags at row w*16; acc[4][1];
// vmcnt(4)). Grids: gemm1 (64,18), gemm2 (64,16). Trades 1.67x total LDS
// reads for 1.67x co-residency -- justified only by idle pipes.
// attn/prep unchanged from R26 (passing, 69.7).

typedef __attribute__((ext_vector_type(8))) short short8;
typedef __attribute__((ext_vector_type(4))) short short4_t;
typedef __attribute__((ext_vector_type(4))) float f32x4;

#define MFMA16(a, b, c) __builtin_amdgcn_mfma_f32_16x16x32_bf16((a), (b), (c), 0, 0, 0)

// scale (1/sqrt(dk)) * log2(e), folded into wq/bq at prep time
#define SCALE_Q 0.1803368801111244f

__device__ inline void gload_lds16(const void* g, void* l) {
  __builtin_amdgcn_global_load_lds(
      (const __attribute__((address_space(1))) void*)g,
      (__attribute__((address_space(3))) void*)l, 16, 0, 0);
}

__device__ inline float fast_exp2(float x) {
  float r;
  asm("v_exp_f32 %0, %1" : "=v"(r) : "v"(x));
  return r;
}

// float -> bf16 bits, round-to-nearest-even (inputs are finite)
__device__ inline short f2bf(float f) {
  union { float f; uint32_t u; } v;
  v.f = f;
  uint32_t u = v.u;
  return (short)((u + 0x7fffu + ((u >> 16) & 1u)) >> 16);
}

// pack two f32 -> 2 bf16 (RNE), one instruction
__device__ inline uint32_t pk_bf16(float lo, float hi) {
  uint32_t r;
  asm("v_cvt_pk_bf16_f32 %0, %1, %2" : "=v"(r) : "v"(lo), "v"(hi));
  return r;
}

__device__ inline int imin(int a, int b) { return a < b ? a : b; }

// ---------------- fused prep kernel ----------------
// blocks [0,288): wq/wk/wv transpose 64x64 tiles via LDS (heavy ->
// dispatched first); block 288: fused bias; [289,801): x cast, 4 x
// 2048-elem chunks per block. wot transpose lives in k_attn now.
__global__ __launch_bounds__(256) void k_prep(
    const float* __restrict__ x, const float* __restrict__ wq,
    const float* __restrict__ wk, const float* __restrict__ wv,
    const float* __restrict__ bq, const float* __restrict__ bk,
    const float* __restrict__ bv,
    short* __restrict__ xb, short* __restrict__ wqkvt,
    float* __restrict__ biasq) {
  const int blk = blockIdx.x;
  const int t = threadIdx.x;
  if (blk >= 289) {
    const int base = (blk - 289) * 8192;
#pragma unroll
    for (int it = 0; it < 4; ++it) {
      const int i = base + it * 2048 + t * 8;
      const float* xp = x + i;
      short8 o;
#pragma unroll
      for (int j = 0; j < 8; ++j) o[j] = f2bf(xp[j]);
      *(short8*)(xb + i) = o;
    }
    return;
  }
  if (blk == 288) {
    for (int idx = t; idx < 1152; idx += 256)
      biasq[idx] = idx < 1024 ? bq[idx] * SCALE_Q
                              : (idx < 1088 ? bk[idx - 1024] : bv[idx - 1088]);
    return;
  }
  __shared__ float lds[64][65];
  const int j = blk;
  const float* src;
  int ncol, k0, n0, row0;
  float sc = 1.f;
  if (j < 256)      { src = wq; ncol = 1024; k0 = (j >> 4) * 64;
                      n0 = (j & 15) * 64; row0 = n0; sc = SCALE_Q; }
  else if (j < 272) { src = wk; ncol = 64; k0 = (j - 256) * 64;
                      n0 = 0; row0 = 1024; }
  else              { src = wv; ncol = 64; k0 = (j - 272) * 64;
                      n0 = 0; row0 = 1088; }
#pragma unroll
  for (int i = 0; i < 4; ++i) {
    int f = i * 256 + t;
    int k = f >> 4, c = f & 15;
    const float* sp = src + (size_t)(k0 + k) * ncol + n0 + c * 4;
#pragma unroll
    for (int q = 0; q < 4; ++q) lds[k][c * 4 + q] = sp[q];
  }
  __syncthreads();
#pragma unroll
  for (int i = 0; i < 2; ++i) {
    int f = i * 256 + t;
    int n = f >> 3, kc = f & 7;
    short8 o;
#pragma unroll
    for (int q = 0; q < 8; ++q) o[q] = f2bf(lds[kc * 8 + q][n] * sc);
    *(short8*)(wqkvt + (size_t)(row0 + n) * 1024 + k0 + kc * 8) = o;
  }
}

// ---------------- GEMM: tile 64x64 (MxN), BK=64, double-buffered ----------
// C[M][ldc] = A[M][1024] @ Bt[N][1024]^T + bias. 4 waves; wave w covers all
// 64 rows x 16 cols [w*16, w*16+16). Counted vmcnt(4), one raw barrier per
// K-step, XOR-swizzled LDS (slot (row,c) holds global chunk c^(row&7)) for
// conflict-free b128 reads. LDS 32KB -> 5 blocks/CU (20 waves).
// vt_out != nullptr (gemm1): V columns (col >= 1088) are ALSO written
// transposed+permuted into vt: V row y -> position pi^-1(y),
// pi^-1(y) = 32*y1 + 16*y3 + 8*y2 + 4*y5 + 2*y4 + y0.
__global__ __launch_bounds__(256, 5) void k_gemm(const short* __restrict__ A,
                                                 const short* __restrict__ Bt,
                                                 const float* __restrict__ bias,
                                                 void* __restrict__ C, int ldc,
                                                 int out_bf16,
                                                 short* __restrict__ vt_out) {
  __shared__ short As[2][4096];  // [64 rows][64 k] 8KB each
  __shared__ short Bs[2][4096];  // [64 rows][64 k] 8KB each
  const int t = threadIdx.x;
  const int w = t >> 6, l = t & 63;
  const int l15 = l & 15, lhi = l >> 4;
  const int m0 = blockIdx.x * 64, n0 = blockIdx.y * 64;

  f32x4 acc[4];
#pragma unroll
  for (int i = 0; i < 4; ++i)
#pragma unroll
    for (int r = 0; r < 4; ++r) acc[i][r] = 0.f;

  const int fA0 = w * 64 + l;
  const int rA0 = fA0 >> 3, gA0 = (fA0 & 7) ^ (rA0 & 7);
  const int fA1 = fA0 + 256;
  const int rA1 = fA1 >> 3, gA1 = (fA1 & 7) ^ (rA1 & 7);

  const int aoff = l15 * 128 + ((lhi ^ (l15 & 7)) << 4);
  const int coff = l15 * 128 + (((4 + lhi) ^ (l15 & 7)) << 4);

  // A: rows rA0 (0..31) + rA1 (32..63), dest linear f*16B. B: same formula,
  // 512 chunks = 2/thread (q<2), dest Bs + f*16B = q*2048 + w*512 + l*8 shorts.
#define GEMM_STAGE(buf, k0)                                                    \
  {                                                                            \
    gload_lds16(A + (size_t)(m0 + rA0) * 1024 + (k0) + gA0 * 8,               \
                &As[buf][w * 512]);                                            \
    gload_lds16(A + (size_t)(m0 + rA1) * 1024 + (k0) + gA1 * 8,               \
                &As[buf][2048 + w * 512]);                                     \
    _Pragma("unroll")                                                          \
    for (int q = 0; q < 2; ++q) {                                              \
      int f = q * 256 + fA0;                                                   \
      int r = f >> 3, gc = (f & 7) ^ (r & 7);                                  \
      gload_lds16(Bt + (size_t)(n0 + r) * 1024 + (k0) + gc * 8,               \
                  &Bs[buf][q * 2048 + w * 512]);                               \
    }                                                                          \
  }

  GEMM_STAGE(0, 0);

  for (int ks = 0; ks < 16; ++ks) {
    const int nb = (ks + 1) & 1;
    GEMM_STAGE(nb, imin(ks + 1, 15) * 64);
    asm volatile("s_waitcnt vmcnt(4)" ::: "memory");

    const char* as = (const char*)&As[ks & 1][0];
    const char* bs = (const char*)&Bs[ks & 1][0];
    short8 afA[4], afB[4], bfA, bfB;
#pragma unroll
    for (int i = 0; i < 4; ++i) {
      afA[i] = *(const short8*)(as + i * 2048 + aoff);
      afB[i] = *(const short8*)(as + i * 2048 + coff);
    }
    bfA = *(const short8*)(bs + (w * 16) * 128 + aoff);
    bfB = *(const short8*)(bs + (w * 16) * 128 + coff);
#pragma unroll
    for (int i = 0; i < 4; ++i) {
      acc[i] = MFMA16(afA[i], bfA, acc[i]);
      acc[i] = MFMA16(afB[i], bfB, acc[i]);
    }
    __builtin_amdgcn_s_barrier();
  }
  asm volatile("s_waitcnt vmcnt(0)" ::: "memory");

  {
    int col = n0 + w * 16 + l15;
    float bia = bias[col];
#pragma unroll
    for (int i = 0; i < 4; ++i) {
      int row0 = m0 + i * 16 + lhi * 4;
      if (out_bf16) {
#pragma unroll
        for (int r = 0; r < 4; ++r)
          ((short*)C)[(size_t)(row0 + r) * ldc + col] =
              (short)(pk_bf16(acc[i][r] + bia, 0.f) & 0xffff);
        // fused V transpose (gemm1 only, V columns): vt[b][d][pos] where
        // pos = T*64 + pi^-1(rho&63); 4-row group (y1y0=0) -> 2 packed
        // dword stores at {pb, pb+1} and {pb+32, pb+33}.
        if (vt_out != nullptr && col >= 1088) {
          const int d = col - 1088;
          const int bb = row0 >> 11, rho = row0 & 2047;
          const int T = rho >> 6, y = rho & 63;
          const int pb = 16 * ((y >> 3) & 1) + 8 * ((y >> 2) & 1) +
                         4 * ((y >> 5) & 1) + 2 * ((y >> 4) & 1);
          short* vp = vt_out + (size_t)(bb * 64 + d) * 2048 + T * 64 + pb;
          *(uint32_t*)(vp) = pk_bf16(acc[i][0] + bia, acc[i][1] + bia);
          *(uint32_t*)(vp + 32) = pk_bf16(acc[i][2] + bia, acc[i][3] + bia);
        }
      } else {
#pragma unroll
        for (int r = 0; r < 4; ++r)
          ((float*)C)[(size_t)(row0 + r) * ldc + col] = acc[i][r] + bia;
      }
    }
  }
#undef GEMM_STAGE
}

// ---------------- flash attention v13 + masked-tile skip + wot piggyback ---
// blocks [0,512): R13-exact attn, except waves skip tiles with tt > ttdiag
// (fully masked -> exact +0 contribution; wave-uniform guard, no barriers
// inside). blocks [512,768): wot 64x64 transpose tiles (512 thr; reuse smem
// as [64][65] f32) -- wot is only consumed by gemm2 and backfills attn's
// idle CU capacity.
__global__ __launch_bounds__(512, 4) void k_attn(const short* __restrict__ qkv,
                                                 const short* __restrict__ vt,
                                                 short* __restrict__ attnb,
                                                 const float* __restrict__ wo,
                                                 short* __restrict__ wot) {
  // LDS: K[g2][db] at g2*16384 + db*8192 (0..32K); V same at 32768+...
  __shared__ char smem[65536];
  const int t = threadIdx.x;
  const int bx = blockIdx.x;

  if (bx >= 512) {  // ---- wot transpose tile (uniform branch) ----
    const int jj = bx - 512;
    const int k0 = (jj >> 4) * 64, n0v = (jj & 15) * 64;
    float(*lds)[65] = (float(*)[65])smem;
#pragma unroll
    for (int i = 0; i < 2; ++i) {
      int f = i * 512 + t;
      int k = f >> 4, c = f & 15;
      const float* sp = wo + (size_t)(k0 + k) * 1024 + n0v + c * 4;
#pragma unroll
      for (int q = 0; q < 4; ++q) lds[k][c * 4 + q] = sp[q];
    }
    __syncthreads();
    {
      int n = t >> 3, kc = t & 7;
      short8 o;
#pragma unroll
      for (int q = 0; q < 8; ++q) o[q] = f2bf(lds[kc * 8 + q][n]);
      *(short8*)(wot + (size_t)(n0v + n) * 1024 + k0 + kc * 8) = o;
    }
    return;
  }

  const int w = t >> 6, l = t & 63;
  const int l15 = l & 15, lhi = l >> 4;
  const int qw = w & 3, g2 = w >> 2;
  const int o = bx >> 5, gg = o & 7;
  const int p = (o < 8) ? gg : 15 - gg;  // balanced: CU's 2 blocks sum 34 tiles
  const int bh = bx & 31, b = bh >> 4, h = bh & 15;
  const int nph = p + 1;
  const short* kb = qkv + (size_t)(b * 2048) * 1152 + 1024;
  const short* vb = vt + (size_t)b * 64 * 2048;

  // staging lane geometry: wave w covers rows w*8..w*8+7 (8 waves = 64 rows);
  // LDS slot (row, c) holds global chunk c ^ (row&7)
  const int srow = w * 8 + (l >> 3);
  const int gcol = (l & 7) ^ (l >> 3);
  const short* kS = kb + (size_t)srow * 1152 + gcol * 8;
  const short* vS = vb + (size_t)srow * 2048 + gcol * 8;

  // frag read byte offsets (row = f*16 + l15, row stride 128B)
  const int aoff = l15 * 128 + ((lhi ^ (l15 & 7)) << 4);
  const int coff = l15 * 128 + (((4 + lhi) ^ (l15 & 7)) << 4);

  short8 ones;
#pragma unroll
  for (int j = 0; j < 8; ++j) ones[j] = (short)0x3F80;  // bf16 1.0

  const int qbase = p * 128 + qw * 32;
  const int myq0 = qbase + l15;        // q-group A
  const int myq1 = qbase + 16 + l15;   // q-group B
  const int ttdiag = qbase >> 6;       // same for both groups (qbase%64 in {0,32})

  const short* qp0 = qkv + (size_t)(b * 2048 + myq0) * 1152 + h * 64 + 8 * lhi;
  const short* qp1 = qkv + (size_t)(b * 2048 + myq1) * 1152 + h * 64 + 8 * lhi;
  short8 qa0 = *(const short8*)(qp0);
  short8 qc0 = *(const short8*)(qp0 + 32);
  short8 qa1 = *(const short8*)(qp1);
  short8 qc1 = *(const short8*)(qp1 + 32);

  f32x4 oo[2][4], o5a, o5b;
#pragma unroll
  for (int qg = 0; qg < 2; ++qg)
#pragma unroll
    for (int fd = 0; fd < 4; ++fd)
#pragma unroll
      for (int r = 0; r < 4; ++r) oo[qg][fd][r] = 0.f;
#pragma unroll
  for (int r = 0; r < 4; ++r) { o5a[r] = 0.f; o5b[r] = 0.f; }

  // prologue: stage tiles 0 (->K[0][0],V[0][0]) and 1 (->K[1][0],V[1][0])
  gload_lds16(kS, smem + w * 1024);
  gload_lds16(kS + 73728, smem + 16384 + w * 1024);
  gload_lds16(vS, smem + 32768 + w * 1024);
  gload_lds16(vS + 64, smem + 32768 + 16384 + w * 1024);
  __syncthreads();

#pragma unroll 1
  for (int i = 0; i < nph; ++i) {
    // stage phase i+1 tiles (2i+2 -> group0 buf, 2i+3 -> group1 buf)
    if (i + 1 < nph) {
      const int nb = (i + 1) & 1;
      const size_t ko2 = (size_t)(2 * i + 2) * 73728;
      const int vo2 = (2 * i + 2) * 64;
      gload_lds16(kS + ko2, smem + nb * 8192 + w * 1024);
      gload_lds16(kS + ko2 + 73728, smem + 16384 + nb * 8192 + w * 1024);
      gload_lds16(vS + vo2, smem + 32768 + nb * 8192 + w * 1024);
      gload_lds16(vS + vo2 + 64, smem + 32768 + 16384 + nb * 8192 + w * 1024);
      __builtin_amdgcn_sched_barrier(0);
    }

    const int tt = 2 * i + g2;
    const int cb = i & 1;

    // skip fully-masked tiles (tt > ttdiag): contribution is exactly +0.
    // wave-uniform; no barriers inside the guarded body.
    if (tt <= ttdiag) {
      // K frags (shared by both q-groups); S^T = K Q^T for both groups
      const char* kr = smem + g2 * 16384 + cb * 8192;
      f32x4 s0[4], s1[4];
      __builtin_amdgcn_s_setprio(1);
#pragma unroll
      for (int f = 0; f < 4; ++f) {
        short8 ka = *(const short8*)(kr + f * 2048 + aoff);
        short8 kc = *(const short8*)(kr + f * 2048 + coff);
        f32x4 z0 = {0.f, 0.f, 0.f, 0.f};
        z0 = MFMA16(ka, qa0, z0);
        z0 = MFMA16(kc, qc0, z0);
        s0[f] = z0;
        f32x4 z1 = {0.f, 0.f, 0.f, 0.f};
        z1 = MFMA16(ka, qa1, z1);
        z1 = MFMA16(kc, qc1, z1);
        s1[f] = z1;
      }
      __builtin_amdgcn_s_setprio(0);

      // causal mask: needed whenever tile reaches/passes the q rows
      if (tt >= ttdiag) {
        const int t0 = tt * 64;
#pragma unroll
        for (int f = 0; f < 4; ++f) {
          int kvb = t0 + f * 16 + lhi * 4;
#pragma unroll
          for (int r = 0; r < 4; ++r) {
            s0[f][r] = (kvb + r <= myq0) ? s0[f][r] : -1e30f;
            s1[f][r] = (kvb + r <= myq1) ? s1[f][r] : -1e30f;
          }
        }
      }

      // p = exp2(s), fixed zero bias (see R12 rationale)
#pragma unroll
      for (int f = 0; f < 4; ++f)
#pragma unroll
        for (int r = 0; r < 4; ++r) {
          s0[f][r] = fast_exp2(s0[f][r]);
          s1[f][r] = fast_exp2(s1[f][r]);
        }

      union { short8 v; uint32_t d[4]; } pA0, pB0, pA1, pB1;
#pragma unroll
      for (int f = 0; f < 4; ++f) {
        pA0.d[f] = pk_bf16(s0[f][0], s0[f][1]);
        pB0.d[f] = pk_bf16(s0[f][2], s0[f][3]);
        pA1.d[f] = pk_bf16(s1[f][0], s1[f][1]);
        pB1.d[f] = pk_bf16(s1[f][2], s1[f][3]);
      }

      // V frags (shared); O^T += V^T P^T per group; l via ones-MFMA
      const char* vr = smem + 32768 + g2 * 16384 + cb * 8192;
      __builtin_amdgcn_s_setprio(1);
#pragma unroll
      for (int fd = 0; fd < 4; ++fd) {
        short8 va = *(const short8*)(vr + fd * 2048 + aoff);
        short8 vc = *(const short8*)(vr + fd * 2048 + coff);
        oo[0][fd] = MFMA16(va, pA0.v, oo[0][fd]);
        oo[0][fd] = MFMA16(vc, pB0.v, oo[0][fd]);
        oo[1][fd] = MFMA16(va, pA1.v, oo[1][fd]);
        oo[1][fd] = MFMA16(vc, pB1.v, oo[1][fd]);
      }
      o5a = MFMA16(ones, pA0.v, o5a);
      o5a = MFMA16(ones, pB0.v, o5a);
      o5b = MFMA16(ones, pA1.v, o5b);
      o5b = MFMA16(ones, pB1.v, o5b);
      __builtin_amdgcn_s_setprio(0);
    }

    __syncthreads();  // staged tiles landed; all reads of current bufs done
  }

  // merge groups (exact addition thanks to fixed-bias softmax), write out.
  // scratch overlaps K bufs (safe: after final barrier, compute done).
  float* scr = (float*)smem;
  float* sp = scr + ((qw << 6) + l) * 34;
  if (g2 == 1) {
#pragma unroll
    for (int qg = 0; qg < 2; ++qg)
#pragma unroll
      for (int fd = 0; fd < 4; ++fd)
#pragma unroll
        for (int r = 0; r < 4; ++r) sp[qg * 16 + fd * 4 + r] = oo[qg][fd][r];
    sp[32] = o5a[0];
    sp[33] = o5b[0];
  }
  __syncthreads();
  if (g2 == 0) {
#pragma unroll
    for (int qg = 0; qg < 2; ++qg) {
      float lsum = (qg ? o5b[0] : o5a[0]) + sp[32 + qg];
      float inv = 1.f / lsum;
      int myq = qbase + qg * 16 + l15;
      short* op = attnb + (size_t)(b * 2048 + myq) * 1024 + h * 64;
#pragma unroll
      for (int fd = 0; fd < 4; ++fd) {
        union { short4_t s4; uint32_t d[2]; } ov;
        float v0 = (oo[qg][fd][0] + sp[qg * 16 + fd * 4 + 0]) * inv;
        float v1 = (oo[qg][fd][1] + sp[qg * 16 + fd * 4 + 1]) * inv;
        float v2 = (oo[qg][fd][2] + sp[qg * 16 + fd * 4 + 2]) * inv;
        float v3 = (oo[qg][fd][3] + sp[qg * 16 + fd * 4 + 3]) * inv;
        ov.d[0] = pk_bf16(v0, v1);
        ov.d[1] = pk_bf16(v2, v3);
        *(short4_t*)(op + fd * 16 + lhi * 4) = ov.s4;
      }
    }
  }
}

// ---------------- launch ----------------
extern "C" void kernel_launch(void* const* d_in, const int* in_sizes, int n_in,
                              void* d_out, int out_size, void* d_ws, size_t ws_size,
                              hipStream_t stream) {
  const float* x  = (const float*)d_in[0];
  // d_in[1] = mask (causal tril) -- applied analytically
  const float* wq = (const float*)d_in[2];
  const float* bq = (const float*)d_in[3];
  const float* wk = (const float*)d_in[4];
  const float* bk = (const float*)d_in[5];
  const float* wv = (const float*)d_in[6];
  const float* bv = (const float*)d_in[7];
  const float* wo = (const float*)d_in[8];
  const float* bo = (const float*)d_in[9];

  char* ws = (char*)d_ws;
  short* xb    = (short*)(ws + 0);          // [4096][1024] bf16   8 MB
  short* qkv   = (short*)(ws + 8388608);    // [4096][1152] bf16   9 MB
  short* wqkvt = (short*)(ws + 17825792);   // [1152][1024] bf16   2.25 MB
  short* wot   = (short*)(ws + 20185088);   // [1024][1024] bf16   2 MB
  short* vt    = (short*)(ws + 22282240);   // [2][64][2048] bf16  0.5 MB
  short* attnb = (short*)(ws + 22806528);   // [4096][1024] bf16   8 MB
  float* biasq = (float*)(ws + 31195136);   // [1152] f32

  k_prep<<<801, 256, 0, stream>>>(x, wq, wk, wv, bq, bk, bv,
                                  xb, wqkvt, biasq);
  k_gemm<<<dim3(64, 18), 256, 0, stream>>>(xb, wqkvt, biasq, qkv, 1152, 1, vt);
  k_attn<<<768, 512, 0, stream>>>(qkv, vt, attnb, wo, wot);
  k_gemm<<<dim3(64, 16), 256, 0, stream>>>(attnb, wot, bo, d_out, 1024, 0,
                                           nullptr);
}

// Round 15
// 69.437 us; speedup vs baseline: 1.0813x; 1.0813x over previous
//
#include <hip/hip_runtime.h>
#include <hip/hip_bf16.h>
#include <stdint.h>

// MQA attention, bf16 MFMA pipeline.
// B=2, S=2048, D_MODEL=1024, H=16, DK=64. Causal mask applied analytically.
//
// R28 (FINAL, converged): identical to R26 (best verified family: 69.7us).
// R27 closed the gemm design space from the second side (64x64/5-blocks
// regressed to 75.1 like 64x64-wave variants before it) -> 64x128/4-wave
// gemm and R13-structure attn are bracketed local optima. Session wins:
// k_vt fused into gemm1 epilogue (-2us), prep reorder+MLP, wot transpose
// backfilled into attn's idle grid, masked-tile skip (exact +0).

typedef __attribute__((ext_vector_type(8))) short short8;
typedef __attribute__((ext_vector_type(4))) short short4_t;
typedef __attribute__((ext_vector_type(4))) float f32x4;

#define MFMA16(a, b, c) __builtin_amdgcn_mfma_f32_16x16x32_bf16((a), (b), (c), 0, 0, 0)

// scale (1/sqrt(dk)) * log2(e), folded into wq/bq at prep time
#define SCALE_Q 0.1803368801111244f

__device__ inline void gload_lds16(const void* g, void* l) {
  __builtin_amdgcn_global_load_lds(
      (const __attribute__((address_space(1))) void*)g,
      (__attribute__((address_space(3))) void*)l, 16, 0, 0);
}

__device__ inline float fast_exp2(float x) {
  float r;
  asm("v_exp_f32 %0, %1" : "=v"(r) : "v"(x));
  return r;
}

// float -> bf16 bits, round-to-nearest-even (inputs are finite)
__device__ inline short f2bf(float f) {
  union { float f; uint32_t u; } v;
  v.f = f;
  uint32_t u = v.u;
  return (short)((u + 0x7fffu + ((u >> 16) & 1u)) >> 16);
}

// pack two f32 -> 2 bf16 (RNE), one instruction
__device__ inline uint32_t pk_bf16(float lo, float hi) {
  uint32_t r;
  asm("v_cvt_pk_bf16_f32 %0, %1, %2" : "=v"(r) : "v"(lo), "v"(hi));
  return r;
}

__device__ inline int imin(int a, int b) { return a < b ? a : b; }

// ---------------- fused prep kernel ----------------
// blocks [0,288): wq/wk/wv transpose 64x64 tiles via LDS (heavy ->
// dispatched first); block 288: fused bias; [289,801): x cast, 4 x
// 2048-elem chunks per block. wot transpose lives in k_attn now.
__global__ __launch_bounds__(256) void k_prep(
    const float* __restrict__ x, const float* __restrict__ wq,
    const float* __restrict__ wk, const float* __restrict__ wv,
    const float* __restrict__ bq, const float* __restrict__ bk,
    const float* __restrict__ bv,
    short* __restrict__ xb, short* __restrict__ wqkvt,
    float* __restrict__ biasq) {
  const int blk = blockIdx.x;
  const int t = threadIdx.x;
  if (blk >= 289) {
    const int base = (blk - 289) * 8192;
#pragma unroll
    for (int it = 0; it < 4; ++it) {
      const int i = base + it * 2048 + t * 8;
      const float* xp = x + i;
      short8 o;
#pragma unroll
      for (int j = 0; j < 8; ++j) o[j] = f2bf(xp[j]);
      *(short8*)(xb + i) = o;
    }
    return;
  }
  if (blk == 288) {
    for (int idx = t; idx < 1152; idx += 256)
      biasq[idx] = idx < 1024 ? bq[idx] * SCALE_Q
                              : (idx < 1088 ? bk[idx - 1024] : bv[idx - 1088]);
    return;
  }
  __shared__ float lds[64][65];
  const int j = blk;
  const float* src;
  int ncol, k0, n0, row0;
  float sc = 1.f;
  if (j < 256)      { src = wq; ncol = 1024; k0 = (j >> 4) * 64;
                      n0 = (j & 15) * 64; row0 = n0; sc = SCALE_Q; }
  else if (j < 272) { src = wk; ncol = 64; k0 = (j - 256) * 64;
                      n0 = 0; row0 = 1024; }
  else              { src = wv; ncol = 64; k0 = (j - 272) * 64;
                      n0 = 0; row0 = 1088; }
#pragma unroll
  for (int i = 0; i < 4; ++i) {
    int f = i * 256 + t;
    int k = f >> 4, c = f & 15;
    const float* sp = src + (size_t)(k0 + k) * ncol + n0 + c * 4;
#pragma unroll
    for (int q = 0; q < 4; ++q) lds[k][c * 4 + q] = sp[q];
  }
  __syncthreads();
#pragma unroll
  for (int i = 0; i < 2; ++i) {
    int f = i * 256 + t;
    int n = f >> 3, kc = f & 7;
    short8 o;
#pragma unroll
    for (int q = 0; q < 8; ++q) o[q] = f2bf(lds[kc * 8 + q][n] * sc);
    *(short8*)(wqkvt + (size_t)(row0 + n) * 1024 + k0 + kc * 8) = o;
  }
}

// ---------------- GEMM: tile 64x128 (MxN), BK=64, double-buffered ----------
// C[M][ldc] = A[M][1024] @ Bt[N][1024]^T + bias. 4 waves; wave w covers all 64
// rows x 32 cols. Counted vmcnt(6), one raw barrier per K-step, XOR-swizzled
// LDS (slot (row,c) holds global chunk c^(row&7)) for conflict-free b128 reads.
// vt_out != nullptr (gemm1): V columns (col >= 1088) are ALSO written
// transposed+permuted into vt: V row y -> position pi^-1(y),
// pi^-1(y) = 32*y1 + 16*y3 + 8*y2 + 4*y5 + 2*y4 + y0.
__global__ __launch_bounds__(256, 3) void k_gemm(const short* __restrict__ A,
                                                 const short* __restrict__ Bt,
                                                 const float* __restrict__ bias,
                                                 void* __restrict__ C, int ldc,
                                                 int out_bf16,
                                                 short* __restrict__ vt_out) {
  __shared__ short As[2][4096];  // [64 rows][64 k] 8KB each
  __shared__ short Bs[2][8192];  // [128 rows][64 k] 16KB each
  const int t = threadIdx.x;
  const int w = t >> 6, l = t & 63;
  const int l15 = l & 15, lhi = l >> 4;
  const int m0 = blockIdx.x * 64, n0 = blockIdx.y * 128;

  f32x4 acc[4][2];
#pragma unroll
  for (int i = 0; i < 4; ++i)
#pragma unroll
    for (int j = 0; j < 2; ++j)
#pragma unroll
      for (int r = 0; r < 4; ++r) acc[i][j][r] = 0.f;

  const int fA0 = w * 64 + l;
  const int rA0 = fA0 >> 3, gA0 = (fA0 & 7) ^ (rA0 & 7);
  const int fA1 = fA0 + 256;
  const int rA1 = fA1 >> 3, gA1 = (fA1 & 7) ^ (rA1 & 7);

  const int aoff = l15 * 128 + ((lhi ^ (l15 & 7)) << 4);
  const int coff = l15 * 128 + (((4 + lhi) ^ (l15 & 7)) << 4);

#define GEMM_STAGE(buf, k0)                                                    \
  {                                                                            \
    gload_lds16(A + (size_t)(m0 + rA0) * 1024 + (k0) + gA0 * 8,               \
                &As[buf][w * 512]);                                            \
    gload_lds16(A + (size_t)(m0 + rA1) * 1024 + (k0) + gA1 * 8,               \
                &As[buf][2048 + w * 512]);                                     \
    _Pragma("unroll")                                                          \
    for (int q = 0; q < 4; ++q) {                                              \
      int f = q * 256 + fA0;                                                   \
      int r = f >> 3, gc = (f & 7) ^ (r & 7);                                  \
      gload_lds16(Bt + (size_t)(n0 + r) * 1024 + (k0) + gc * 8,               \
                  &Bs[buf][q * 2048 + w * 512]);                               \
    }                                                                          \
  }

  GEMM_STAGE(0, 0);

  for (int ks = 0; ks < 16; ++ks) {
    const int nb = (ks + 1) & 1;
    GEMM_STAGE(nb, imin(ks + 1, 15) * 64);
    asm volatile("s_waitcnt vmcnt(6)" ::: "memory");

    const char* as = (const char*)&As[ks & 1][0];
    const char* bs = (const char*)&Bs[ks & 1][0];
    short8 afA[4], afB[4], bfA[2], bfB[2];
#pragma unroll
    for (int i = 0; i < 4; ++i) {
      afA[i] = *(const short8*)(as + i * 2048 + aoff);
      afB[i] = *(const short8*)(as + i * 2048 + coff);
    }
#pragma unroll
    for (int j = 0; j < 2; ++j) {
      bfA[j] = *(const short8*)(bs + (w * 32 + j * 16) * 128 + aoff);
      bfB[j] = *(const short8*)(bs + (w * 32 + j * 16) * 128 + coff);
    }
#pragma unroll
    for (int i = 0; i < 4; ++i)
#pragma unroll
      for (int j = 0; j < 2; ++j) {
        acc[i][j] = MFMA16(afA[i], bfA[j], acc[i][j]);
        acc[i][j] = MFMA16(afB[i], bfB[j], acc[i][j]);
      }
    __builtin_amdgcn_s_barrier();
  }
  asm volatile("s_waitcnt vmcnt(0)" ::: "memory");

#pragma unroll
  for (int j = 0; j < 2; ++j) {
    int col = n0 + w * 32 + j * 16 + l15;
    float bia = bias[col];
#pragma unroll
    for (int i = 0; i < 4; ++i) {
      int row0 = m0 + i * 16 + lhi * 4;
      if (out_bf16) {
#pragma unroll
        for (int r = 0; r < 4; ++r)
          ((short*)C)[(size_t)(row0 + r) * ldc + col] =
              (short)(pk_bf16(acc[i][j][r] + bia, 0.f) & 0xffff);
        // fused V transpose (gemm1 only, V columns): vt[b][d][pos] where
        // pos = T*64 + pi^-1(rho&63); 4-row group (y1y0=0) -> 2 packed
        // dword stores at {pb, pb+1} and {pb+32, pb+33}.
        if (vt_out != nullptr && col >= 1088) {
          const int d = col - 1088;
          const int bb = row0 >> 11, rho = row0 & 2047;
          const int T = rho >> 6, y = rho & 63;
          const int pb = 16 * ((y >> 3) & 1) + 8 * ((y >> 2) & 1) +
                         4 * ((y >> 5) & 1) + 2 * ((y >> 4) & 1);
          short* vp = vt_out + (size_t)(bb * 64 + d) * 2048 + T * 64 + pb;
          *(uint32_t*)(vp) = pk_bf16(acc[i][j][0] + bia, acc[i][j][1] + bia);
          *(uint32_t*)(vp + 32) = pk_bf16(acc[i][j][2] + bia, acc[i][j][3] + bia);
        }
      } else {
#pragma unroll
        for (int r = 0; r < 4; ++r)
          ((float*)C)[(size_t)(row0 + r) * ldc + col] = acc[i][j][r] + bia;
      }
    }
  }
#undef GEMM_STAGE
}

// ---------------- flash attention v13 + masked-tile skip + wot piggyback ---
// blocks [0,512): R13-exact attn, except waves skip tiles with tt > ttdiag
// (fully masked -> exact +0 contribution; wave-uniform guard, no barriers
// inside). blocks [512,768): wot 64x64 transpose tiles (512 thr; reuse smem
// as [64][65] f32) -- wot is only consumed by gemm2 and backfills attn's
// idle CU capacity.
__global__ __launch_bounds__(512, 4) void k_attn(const short* __restrict__ qkv,
                                                 const short* __restrict__ vt,
                                                 short* __restrict__ attnb,
                                                 const float* __restrict__ wo,
                                                 short* __restrict__ wot) {
  // LDS: K[g2][db] at g2*16384 + db*8192 (0..32K); V same at 32768+...
  __shared__ char smem[65536];
  const int t = threadIdx.x;
  const int bx = blockIdx.x;

  if (bx >= 512) {  // ---- wot transpose tile (uniform branch) ----
    const int jj = bx - 512;
    const int k0 = (jj >> 4) * 64, n0v = (jj & 15) * 64;
    float(*lds)[65] = (float(*)[65])smem;
#pragma unroll
    for (int i = 0; i < 2; ++i) {
      int f = i * 512 + t;
      int k = f >> 4, c = f & 15;
      const float* sp = wo + (size_t)(k0 + k) * 1024 + n0v + c * 4;
#pragma unroll
      for (int q = 0; q < 4; ++q) lds[k][c * 4 + q] = sp[q];
    }
    __syncthreads();
    {
      int n = t >> 3, kc = t & 7;
      short8 o;
#pragma unroll
      for (int q = 0; q < 8; ++q) o[q] = f2bf(lds[kc * 8 + q][n]);
      *(short8*)(wot + (size_t)(n0v + n) * 1024 + k0 + kc * 8) = o;
    }
    return;
  }

  const int w = t >> 6, l = t & 63;
  const int l15 = l & 15, lhi = l >> 4;
  const int qw = w & 3, g2 = w >> 2;
  const int o = bx >> 5, gg = o & 7;
  const int p = (o < 8) ? gg : 15 - gg;  // balanced: CU's 2 blocks sum 34 tiles
  const int bh = bx & 31, b = bh >> 4, h = bh & 15;
  const int nph = p + 1;
  const short* kb = qkv + (size_t)(b * 2048) * 1152 + 1024;
  const short* vb = vt + (size_t)b * 64 * 2048;

  // staging lane geometry: wave w covers rows w*8..w*8+7 (8 waves = 64 rows);
  // LDS slot (row, c) holds global chunk c ^ (row&7)
  const int srow = w * 8 + (l >> 3);
  const int gcol = (l & 7) ^ (l >> 3);
  const short* kS = kb + (size_t)srow * 1152 + gcol * 8;
  const short* vS = vb + (size_t)srow * 2048 + gcol * 8;

  // frag read byte offsets (row = f*16 + l15, row stride 128B)
  const int aoff = l15 * 128 + ((lhi ^ (l15 & 7)) << 4);
  const int coff = l15 * 128 + (((4 + lhi) ^ (l15 & 7)) << 4);

  short8 ones;
#pragma unroll
  for (int j = 0; j < 8; ++j) ones[j] = (short)0x3F80;  // bf16 1.0

  const int qbase = p * 128 + qw * 32;
  const int myq0 = qbase + l15;        // q-group A
  const int myq1 = qbase + 16 + l15;   // q-group B
  const int ttdiag = qbase >> 6;       // same for both groups (qbase%64 in {0,32})

  const short* qp0 = qkv + (size_t)(b * 2048 + myq0) * 1152 + h * 64 + 8 * lhi;
  const short* qp1 = qkv + (size_t)(b * 2048 + myq1) * 1152 + h * 64 + 8 * lhi;
  short8 qa0 = *(const short8*)(qp0);
  short8 qc0 = *(const short8*)(qp0 + 32);
  short8 qa1 = *(const short8*)(qp1);
  short8 qc1 = *(const short8*)(qp1 + 32);

  f32x4 oo[2][4], o5a, o5b;
#pragma unroll
  for (int qg = 0; qg < 2; ++qg)
#pragma unroll
    for (int fd = 0; fd < 4; ++fd)
#pragma unroll
      for (int r = 0; r < 4; ++r) oo[qg][fd][r] = 0.f;
#pragma unroll
  for (int r = 0; r < 4; ++r) { o5a[r] = 0.f; o5b[r] = 0.f; }

  // prologue: stage tiles 0 (->K[0][0],V[0][0]) and 1 (->K[1][0],V[1][0])
  gload_lds16(kS, smem + w * 1024);
  gload_lds16(kS + 73728, smem + 16384 + w * 1024);
  gload_lds16(vS, smem + 32768 + w * 1024);
  gload_lds16(vS + 64, smem + 32768 + 16384 + w * 1024);
  __syncthreads();

#pragma unroll 1
  for (int i = 0; i < nph; ++i) {
    // stage phase i+1 tiles (2i+2 -> group0 buf, 2i+3 -> group1 buf)
    if (i + 1 < nph) {
      const int nb = (i + 1) & 1;
      const size_t ko2 = (size_t)(2 * i + 2) * 73728;
      const int vo2 = (2 * i + 2) * 64;
      gload_lds16(kS + ko2, smem + nb * 8192 + w * 1024);
      gload_lds16(kS + ko2 + 73728, smem + 16384 + nb * 8192 + w * 1024);
      gload_lds16(vS + vo2, smem + 32768 + nb * 8192 + w * 1024);
      gload_lds16(vS + vo2 + 64, smem + 32768 + 16384 + nb * 8192 + w * 1024);
      __builtin_amdgcn_sched_barrier(0);
    }

    const int tt = 2 * i + g2;
    const int cb = i & 1;

    // skip fully-masked tiles (tt > ttdiag): contribution is exactly +0.
    // wave-uniform; no barriers inside the guarded body.
    if (tt <= ttdiag) {
      // K frags (shared by both q-groups); S^T = K Q^T for both groups
      const char* kr = smem + g2 * 16384 + cb * 8192;
      f32x4 s0[4], s1[4];
      __builtin_amdgcn_s_setprio(1);
#pragma unroll
      for (int f = 0; f < 4; ++f) {
        short8 ka = *(const short8*)(kr + f * 2048 + aoff);
        short8 kc = *(const short8*)(kr + f * 2048 + coff);
        f32x4 z0 = {0.f, 0.f, 0.f, 0.f};
        z0 = MFMA16(ka, qa0, z0);
        z0 = MFMA16(kc, qc0, z0);
        s0[f] = z0;
        f32x4 z1 = {0.f, 0.f, 0.f, 0.f};
        z1 = MFMA16(ka, qa1, z1);
        z1 = MFMA16(kc, qc1, z1);
        s1[f] = z1;
      }
      __builtin_amdgcn_s_setprio(0);

      // causal mask: needed whenever tile reaches/passes the q rows
      if (tt >= ttdiag) {
        const int t0 = tt * 64;
#pragma unroll
        for (int f = 0; f < 4; ++f) {
          int kvb = t0 + f * 16 + lhi * 4;
#pragma unroll
          for (int r = 0; r < 4; ++r) {
            s0[f][r] = (kvb + r <= myq0) ? s0[f][r] : -1e30f;
            s1[f][r] = (kvb + r <= myq1) ? s1[f][r] : -1e30f;
          }
        }
      }

      // p = exp2(s), fixed zero bias (see R12 rationale)
#pragma unroll
      for (int f = 0; f < 4; ++f)
#pragma unroll
        for (int r = 0; r < 4; ++r) {
          s0[f][r] = fast_exp2(s0[f][r]);
          s1[f][r] = fast_exp2(s1[f][r]);
        }

      union { short8 v; uint32_t d[4]; } pA0, pB0, pA1, pB1;
#pragma unroll
      for (int f = 0; f < 4; ++f) {
        pA0.d[f] = pk_bf16(s0[f][0], s0[f][1]);
        pB0.d[f] = pk_bf16(s0[f][2], s0[f][3]);
        pA1.d[f] = pk_bf16(s1[f][0], s1[f][1]);
        pB1.d[f] = pk_bf16(s1[f][2], s1[f][3]);
      }

      // V frags (shared); O^T += V^T P^T per group; l via ones-MFMA
      const char* vr = smem + 32768 + g2 * 16384 + cb * 8192;
      __builtin_amdgcn_s_setprio(1);
#pragma unroll
      for (int fd = 0; fd < 4; ++fd) {
        short8 va = *(const short8*)(vr + fd * 2048 + aoff);
        short8 vc = *(const short8*)(vr + fd * 2048 + coff);
        oo[0][fd] = MFMA16(va, pA0.v, oo[0][fd]);
        oo[0][fd] = MFMA16(vc, pB0.v, oo[0][fd]);
        oo[1][fd] = MFMA16(va, pA1.v, oo[1][fd]);
        oo[1][fd] = MFMA16(vc, pB1.v, oo[1][fd]);
      }
      o5a = MFMA16(ones, pA0.v, o5a);
      o5a = MFMA16(ones, pB0.v, o5a);
      o5b = MFMA16(ones, pA1.v, o5b);
      o5b = MFMA16(ones, pB1.v, o5b);
      __builtin_amdgcn_s_setprio(0);
    }

    __syncthreads();  // staged tiles landed; all reads of current bufs done
  }

  // merge groups (exact addition thanks to fixed-bias softmax), write out.
  // scratch overlaps K bufs (safe: after final barrier, compute done).
  float* scr = (float*)smem;
  float* sp = scr + ((qw << 6) + l) * 34;
  if (g2 == 1) {
#pragma unroll
    for (int qg = 0; qg < 2; ++qg)
#pragma unroll
      for (int fd = 0; fd < 4; ++fd)
#pragma unroll
        for (int r = 0; r < 4; ++r) sp[qg * 16 + fd * 4 + r] = oo[qg][fd][r];
    sp[32] = o5a[0];
    sp[33] = o5b[0];
  }
  __syncthreads();
  if (g2 == 0) {
#pragma unroll
    for (int qg = 0; qg < 2; ++qg) {
      float lsum = (qg ? o5b[0] : o5a[0]) + sp[32 + qg];
      float inv = 1.f / lsum;
      int myq = qbase + qg * 16 + l15;
      short* op = attnb + (size_t)(b * 2048 + myq) * 1024 + h * 64;
#pragma unroll
      for (int fd = 0; fd < 4; ++fd) {
        union { short4_t s4; uint32_t d[2]; } ov;
        float v0 = (oo[qg][fd][0] + sp[qg * 16 + fd * 4 + 0]) * inv;
        float v1 = (oo[qg][fd][1] + sp[qg * 16 + fd * 4 + 1]) * inv;
        float v2 = (oo[qg][fd][2] + sp[qg * 16 + fd * 4 + 2]) * inv;
        float v3 = (oo[qg][fd][3] + sp[qg * 16 + fd * 4 + 3]) * inv;
        ov.d[0] = pk_bf16(v0, v1);
        ov.d[1] = pk_bf16(v2, v3);
        *(short4_t*)(op + fd * 16 + lhi * 4) = ov.s4;
      }
    }
  }
}

// ---------------- launch ----------------
extern "C" void kernel_launch(void* const* d_in, const int* in_sizes, int n_in,
                              void* d_out, int out_size, void* d_ws, size_t ws_size,
                              hipStream_t stream) {
  const float* x  = (const float*)d_in[0];
  // d_in[1] = mask (causal tril) -- applied analytically
  const float* wq = (const float*)d_in[2];
  const float* bq = (const float*)d_in[3];
  const float* wk = (const float*)d_in[4];
  const float* bk = (const float*)d_in[5];
  const float* wv = (const float*)d_in[6];
  const float* bv = (const float*)d_in[7];
  const float* wo = (const float*)d_in[8];
  const float* bo = (const float*)d_in[9];

  char* ws = (char*)d_ws;
  short* xb    = (short*)(ws + 0);          // [4096][1024] bf16   8 MB
  short* qkv   = (short*)(ws + 8388608);    // [4096][1152] bf16   9 MB
  short* wqkvt = (short*)(ws + 17825792);   // [1152][1024] bf16   2.25 MB
  short* wot   = (short*)(ws + 20185088);   // [1024][1024] bf16   2 MB
  short* vt    = (short*)(ws + 22282240);   // [2][64][2048] bf16  0.5 MB
  short* attnb = (short*)(ws + 22806528);   // [4096][1024] bf16   8 MB
  float* biasq = (float*)(ws + 31195136);   // [1152] f32

  k_prep<<<801, 256, 0, stream>>>(x, wq, wk, wv, bq, bk, bv,
                                  xb, wqkvt, biasq);
  k_gemm<<<dim3(64, 9), 256, 0, stream>>>(xb, wqkvt, biasq, qkv, 1152, 1, vt);
  k_attn<<<768, 512, 0, stream>>>(qkv, vt, attnb, wo, wot);
  k_gemm<<<dim3(64, 8), 256, 0, stream>>>(attnb, wot, bo, d_out, 1024, 0,
                                          nullptr);
}